// Round 5
// baseline (385.338 us; speedup 1.0000x reference)
//
#include <hip/hip_runtime.h>

#define HEADS 4
#define DH 64
#define NHID 256   // HEADS*DH
#define KIN 256
#define NEG_SLOPE 0.2f

typedef __attribute__((ext_vector_type(8))) short short8;
typedef __attribute__((ext_vector_type(4))) float f32x4;

__device__ inline float bf2f(unsigned short u) {
  union { unsigned int i; float f; } v; v.i = ((unsigned int)u) << 16; return v.f;
}
__device__ inline unsigned short f2bf(float f) {
  union { float f; unsigned int i; } v; v.f = f;
  unsigned int r = v.i + 0x7FFF + ((v.i >> 16) & 1);  // RNE
  return (unsigned short)(r >> 16);
}

// -------- k_cvtW: W[k][n] fp32 -> Wt[n][k] bf16 (transpose+convert, tiny)
__global__ void k_cvtW(const float* __restrict__ W, unsigned short* __restrict__ Wt) {
  int n = blockIdx.x, k = threadIdx.x;
  Wt[n * 256 + k] = f2bf(W[k * 256 + n]);
}

// -------- k_gemm: fused projection + logits, BM=128, 8 waves, double-buffered LDS.
// ftb[M][256] bf16 = bf16(feat) @ Wt^T;  el/er[M][4] from fp32 accumulator.
// Wave w: rows (w>>2)*64..+64, cols (w&3)*64..+64 (head = w&3).
__global__ __launch_bounds__(512, 2) void k_gemm(
    const float* __restrict__ feat, const unsigned short* __restrict__ Wt,
    const float* __restrict__ al, const float* __restrict__ ar,
    unsigned short* __restrict__ ftb, float* __restrict__ el,
    float* __restrict__ er, int M)
{
  __shared__ unsigned short As[2][128 * 32];   // 2 x 8 KB
  __shared__ unsigned short Bs[2][256 * 32];   // 2 x 16 KB
  const int t = threadIdx.x;       // 0..511
  const int lane = t & 63;
  const int w = t >> 6;            // 0..7
  const int wr = w >> 2;           // row block 0..1
  const int hc = w & 3;            // head == col block
  const int row0 = blockIdx.x * 128;

  f32x4 acc[4][4] = {};

  // A staging: thread t -> row ra (0..127), k-chunk ca (0..3), swizzled LDS slot
  const int ra = t >> 2, ca = t & 3;
  const int arow = min(row0 + ra, M - 1);
  const int adst = ra * 64 + ((ca ^ ((ra >> 1) & 3)) * 16);

  // B staging: j in {0,1}: lds byte = j*8192 + t*16 (wave-uniform base + lane*16);
  // source row n = j*128 + (t>>2), chunk kc = t&3, pre-swizzled global chunk.
  const int bn0 = t >> 2, bkc = t & 3;

  // ---- prologue: stage k0 = 0 into buffer 0
  {
    const float* ga = feat + (size_t)arow * KIN + ca * 8;
    float4 v0 = *(const float4*)ga;
    float4 v1 = *(const float4*)(ga + 4);
    short8 pk;
    pk[0] = (short)f2bf(v0.x); pk[1] = (short)f2bf(v0.y);
    pk[2] = (short)f2bf(v0.z); pk[3] = (short)f2bf(v0.w);
    pk[4] = (short)f2bf(v1.x); pk[5] = (short)f2bf(v1.y);
    pk[6] = (short)f2bf(v1.z); pk[7] = (short)f2bf(v1.w);
    *(short8*)((char*)As[0] + adst) = pk;
    #pragma unroll
    for (int j = 0; j < 2; ++j) {
      int n = j * 128 + bn0;
      const unsigned short* gb = Wt + n * 256 + ((bkc ^ ((n >> 1) & 3)) * 8);
      __builtin_amdgcn_global_load_lds(
          (const __attribute__((address_space(1))) void*)gb,
          (__attribute__((address_space(3))) void*)((char*)Bs[0] + j * 8192 + t * 16),
          16, 0, 0);
    }
  }
  __syncthreads();

  int cur = 0;
  for (int kt = 0; kt < 8; ++kt) {
    // issue next tile's loads before compute
    float4 nv0, nv1;
    if (kt < 7) {
      int k0 = (kt + 1) * 32;
      const float* ga = feat + (size_t)arow * KIN + k0 + ca * 8;
      nv0 = *(const float4*)ga;
      nv1 = *(const float4*)(ga + 4);
      #pragma unroll
      for (int j = 0; j < 2; ++j) {
        int n = j * 128 + bn0;
        const unsigned short* gb = Wt + n * 256 + k0 + ((bkc ^ ((n >> 1) & 3)) * 8);
        __builtin_amdgcn_global_load_lds(
            (const __attribute__((address_space(1))) void*)gb,
            (__attribute__((address_space(3))) void*)((char*)Bs[cur ^ 1] + j * 8192 + t * 16),
            16, 0, 0);
      }
    }
    // compute on buffer cur
    const int i = lane & 15, kc = lane >> 4;
    short8 af[4], bf[4];
    #pragma unroll
    for (int m = 0; m < 4; ++m) {
      int r = wr * 64 + m * 16 + i;
      af[m] = *(const short8*)((const char*)As[cur] + r * 64 + ((kc ^ ((r >> 1) & 3)) * 16));
    }
    #pragma unroll
    for (int n = 0; n < 4; ++n) {
      int nr = hc * 64 + n * 16 + i;
      bf[n] = *(const short8*)((const char*)Bs[cur] + nr * 64 + ((kc ^ ((nr >> 1) & 3)) * 16));
    }
    #pragma unroll
    for (int m = 0; m < 4; ++m)
      #pragma unroll
      for (int n = 0; n < 4; ++n)
        acc[m][n] = __builtin_amdgcn_mfma_f32_16x16x32_bf16(af[m], bf[n], acc[m][n], 0, 0, 0);
    // late half of A-stage: convert + ds_write into next buffer
    if (kt < 7) {
      short8 pk;
      pk[0] = (short)f2bf(nv0.x); pk[1] = (short)f2bf(nv0.y);
      pk[2] = (short)f2bf(nv0.z); pk[3] = (short)f2bf(nv0.w);
      pk[4] = (short)f2bf(nv1.x); pk[5] = (short)f2bf(nv1.y);
      pk[6] = (short)f2bf(nv1.z); pk[7] = (short)f2bf(nv1.w);
      *(short8*)((char*)As[cur ^ 1] + adst) = pk;
    }
    __syncthreads();
    cur ^= 1;
  }

  // epilogue: C/D layout col=lane&15, row=(lane>>4)*4+reg  [m89-verified]
  const int ci = lane & 15, rg = lane >> 4;
  #pragma unroll
  for (int m = 0; m < 4; ++m) {
    #pragma unroll
    for (int r = 0; r < 4; ++r) {
      int grow = row0 + wr * 64 + m * 16 + rg * 4 + r;
      if (grow < M) {
        unsigned short* fp = ftb + (size_t)grow * NHID + hc * 64;
        #pragma unroll
        for (int n = 0; n < 4; ++n) fp[n * 16 + ci] = f2bf(acc[m][n][r]);
      }
    }
  }
  float alv[4], arv[4];
  #pragma unroll
  for (int n = 0; n < 4; ++n) {
    alv[n] = al[hc * DH + n * 16 + ci];
    arv[n] = ar[hc * DH + n * 16 + ci];
  }
  #pragma unroll
  for (int m = 0; m < 4; ++m) {
    #pragma unroll
    for (int r = 0; r < 4; ++r) {
      float pl = 0.f, pr = 0.f;
      #pragma unroll
      for (int n = 0; n < 4; ++n) {
        pl += acc[m][n][r] * alv[n];
        pr += acc[m][n][r] * arv[n];
      }
      pl += __shfl_xor(pl, 1); pl += __shfl_xor(pl, 2);
      pl += __shfl_xor(pl, 4); pl += __shfl_xor(pl, 8);
      pr += __shfl_xor(pr, 1); pr += __shfl_xor(pr, 2);
      pr += __shfl_xor(pr, 4); pr += __shfl_xor(pr, 8);
      if (ci == 0) {
        int grow = row0 + wr * 64 + m * 16 + rg * 4 + r;
        if (grow < M) { el[grow * HEADS + hc] = pl; er[grow * HEADS + hc] = pr; }
      }
    }
  }
}

// ---------------- CSR build ----------------
__global__ void k_deg(const int* __restrict__ dst, int* __restrict__ deg, int E) {
  int e = blockIdx.x * 256 + threadIdx.x;
  if (e < E) atomicAdd(&deg[dst[e]], 1);
}

__global__ __launch_bounds__(1024) void k_scan1(const int* __restrict__ deg,
                                                int* __restrict__ offs,
                                                int* __restrict__ part, int N) {
  __shared__ int s[1024];
  int tid = threadIdx.x;
  int idx = blockIdx.x * 1024 + tid;
  int v = (idx < N) ? deg[idx] : 0;
  s[tid] = v;
  __syncthreads();
  for (int off = 1; off < 1024; off <<= 1) {
    int tmp = (tid >= off) ? s[tid - off] : 0;
    __syncthreads();
    s[tid] += tmp;
    __syncthreads();
  }
  if (idx < N) offs[idx] = s[tid] - v;
  if (tid == 1023) part[blockIdx.x] = s[1023];
}

__global__ __launch_bounds__(128) void k_scan2(const int* __restrict__ part,
                                               int* __restrict__ pbase, int nb) {
  __shared__ int s[128];
  int tid = threadIdx.x;
  int v = (tid < nb) ? part[tid] : 0;
  s[tid] = v;
  __syncthreads();
  for (int off = 1; off < 128; off <<= 1) {
    int tmp = (tid >= off) ? s[tid - off] : 0;
    __syncthreads();
    s[tid] += tmp;
    __syncthreads();
  }
  if (tid < nb) pbase[tid] = s[tid] - v;
}

__global__ void k_scan3(int* __restrict__ offs, const int* __restrict__ pbase,
                        int N, int E) {
  int idx = blockIdx.x * 256 + threadIdx.x;
  if (idx < N) offs[idx] += pbase[idx >> 10];
  if (idx == N) offs[N] = E;
}

// -------- k_fill: cursor pre-initialized to offs -> single atomic gives final slot
__global__ void k_fill(const int* __restrict__ src, const int* __restrict__ dst,
                       int* __restrict__ cursor, int* __restrict__ csr, int E) {
  int e = blockIdx.x * 256 + threadIdx.x;
  if (e < E) {
    int p = atomicAdd(&cursor[dst[e]], 1);
    csr[p] = src[e];
  }
}

// ---------------- Aggregation: wave per node, quarter-wave per edge ----------------
// 16 lanes per edge, each lane owns 16 dims (2 x ushort8); 4 edges in flight.
// Pipeline: csr prefetched 2 iters ahead, el/ft 1 iter ahead.
__global__ __launch_bounds__(256) void k_aggr(
    const unsigned short* __restrict__ ftb, const float* __restrict__ el,
    const float* __restrict__ er, const int* __restrict__ offs,
    const int* __restrict__ csr, float* __restrict__ out, int N)
{
  int n = blockIdx.x * 4 + (threadIdx.x >> 6);
  int lane = threadIdx.x & 63;
  if (n >= N) return;
  int q  = lane >> 4;          // edge slot 0..3
  int ql = lane & 15;          // dims ql*16 .. ql*16+15
  int hh = ql >> 2;            // head of my dims
  int start = offs[n], end = offs[n + 1];
  const short8* ft8 = (const short8*)ftb;
  float acc[16] = {};
  float ws = 0.f;
  if (end > start) {
    float erh = er[n * HEADS + hh];
    int last = end - 1;
    int eA = start + q;
    int eB = eA + 4;
    int sB = csr[min(eB, last)];
    {
      int sA = csr[min(eA, last)];
      float lxA = el[sA * 4 + hh];
      short8 fa0 = ft8[(size_t)sA * 32 + ql * 2];
      short8 fa1 = ft8[(size_t)sA * 32 + ql * 2 + 1];
      for (int e0 = start; e0 < end; e0 += 4) {
        // prefetch iter+2 csr
        int sC = csr[min(e0 + 8 + q, last)];
        // prefetch iter+1 el/ft (from sB, known since last iter)
        float lxB = el[sB * 4 + hh];
        short8 fb0 = ft8[(size_t)sB * 32 + ql * 2];
        short8 fb1 = ft8[(size_t)sB * 32 + ql * 2 + 1];
        // compute current
        bool v = (e0 + q) < end;
        float x = lxA + erh;
        x = x > 0.f ? x : NEG_SLOPE * x;
        float ex = v ? __expf(x) : 0.f;
        ws += ex;
        #pragma unroll
        for (int j = 0; j < 8; ++j) acc[j]     += ex * bf2f((unsigned short)fa0[j]);
        #pragma unroll
        for (int j = 0; j < 8; ++j) acc[j + 8] += ex * bf2f((unsigned short)fa1[j]);
        // rotate pipeline registers (all static)
        sB = sC; lxA = lxB; fa0 = fb0; fa1 = fb1;
      }
    }
  }
  ws += __shfl_xor(ws, 16); ws += __shfl_xor(ws, 32);
  #pragma unroll
  for (int j = 0; j < 16; ++j) {
    acc[j] += __shfl_xor(acc[j], 16);
    acc[j] += __shfl_xor(acc[j], 32);
  }
  if (q == 0) {
    float inv = (end > start) ? 1.f / ws : 0.f;
    float* op = out + (size_t)n * NHID + ql * 16;
    #pragma unroll
    for (int j4 = 0; j4 < 4; ++j4)
      *(float4*)(op + j4 * 4) = make_float4(acc[j4 * 4] * inv, acc[j4 * 4 + 1] * inv,
                                            acc[j4 * 4 + 2] * inv, acc[j4 * 4 + 3] * inv);
  }
}

// ---------------- launch ----------------
extern "C" void kernel_launch(void* const* d_in, const int* in_sizes, int n_in,
                              void* d_out, int out_size, void* d_ws, size_t ws_size,
                              hipStream_t stream)
{
  const float* feat = (const float*)d_in[0];
  const float* W    = (const float*)d_in[1];
  const float* al   = (const float*)d_in[2];
  const float* ar   = (const float*)d_in[3];
  const int*   src  = (const int*)d_in[4];
  const int*   dst  = (const int*)d_in[5];
  const int M = in_sizes[0] / KIN;   // 100000
  const int E = in_sizes[4];         // 1600000
  float* out = (float*)d_out;

  char* base = (char*)d_ws;
  size_t off = 0;
  auto alloc = [&](size_t b) { char* p = base + off; off = (off + b + 255) & ~(size_t)255; return p; };
  unsigned short* ftb = (unsigned short*)alloc((size_t)M * NHID * sizeof(unsigned short)); // 51.2 MB
  unsigned short* Wt  = (unsigned short*)alloc(256 * 256 * sizeof(unsigned short));
  float* el     = (float*)alloc((size_t)M * HEADS * sizeof(float));
  float* er     = (float*)alloc((size_t)M * HEADS * sizeof(float));
  int*   deg    = (int*)alloc((size_t)M * sizeof(int));
  int*   offs   = (int*)alloc((size_t)(M + 1) * sizeof(int));
  int*   cursor = (int*)alloc((size_t)M * sizeof(int));
  int*   part   = (int*)alloc(1024 * sizeof(int));
  int*   pbase  = (int*)alloc(1024 * sizeof(int));
  int*   csr    = (int*)alloc((size_t)E * sizeof(int));
  (void)ws_size; (void)n_in; (void)out_size;

  hipMemsetAsync(deg, 0, (size_t)M * sizeof(int), stream);

  k_cvtW<<<256, 256, 0, stream>>>(W, Wt);
  k_deg<<<(E + 255) / 256, 256, 0, stream>>>(dst, deg, E);
  int nb = (M + 1023) / 1024;
  k_scan1<<<nb, 1024, 0, stream>>>(deg, offs, part, M);
  k_scan2<<<1, 128, 0, stream>>>(part, pbase, nb);
  k_scan3<<<(M + 1 + 255) / 256, 256, 0, stream>>>(offs, pbase, M, E);
  hipMemcpyAsync(cursor, offs, (size_t)M * sizeof(int), hipMemcpyDeviceToDevice, stream);
  k_gemm<<<(M + 127) / 128, 512, 0, stream>>>(feat, Wt, al, ar, ftb, el, er, M);
  k_fill<<<(E + 255) / 256, 256, 0, stream>>>(src, dst, cursor, csr, E);
  k_aggr<<<(M + 3) / 4, 256, 0, stream>>>(ftb, el, er, offs, csr, out, M);
}